// Round 8
// baseline (278.179 us; speedup 1.0000x reference)
//
#include <hip/hip_runtime.h>
#include <stdint.h>
#include <stddef.h>

#define H  512
#define BB 64
#define TV 512
#define TT 64

typedef short s8v __attribute__((ext_vector_type(8)));   // 8 bf16 (4 VGPRs)
typedef float f4v __attribute__((ext_vector_type(4)));   // MFMA accumulator

// ---- helpers -------------------------------------------------------------

__device__ inline unsigned short f2bf(float f) {
  unsigned int u = __float_as_uint(f);
  u = (u + 0x7fffu + ((u >> 16) & 1u)) >> 16;   // RNE
  return (unsigned short)u;
}

__device__ inline unsigned int pk2bf(float lo, float hi) {
  unsigned int a = __float_as_uint(lo);
  a = (a + 0x7fffu + ((a >> 16) & 1u)) >> 16;
  unsigned int b = __float_as_uint(hi);
  b = (b + 0x7fffu + ((b >> 16) & 1u)) & 0xffff0000u;
  return a | b;
}

__device__ inline float fast_tanh(float x) {
  x = fminf(15.f, fmaxf(-15.f, x));
  float e = __expf(2.f * x);
  return (e - 1.f) * __builtin_amdgcn_rcpf(e + 1.f);
}

// async global->LDS, 16 bytes per lane (global_load_lds_dwordx4).
// R6 lesson: per-lane global addresses must stay monotone/contiguous.
__device__ inline void gld16(const unsigned short* g, unsigned short* l) {
  __builtin_amdgcn_global_load_lds(
      (const __attribute__((address_space(1))) unsigned int*)g,
      (__attribute__((address_space(3))) unsigned int*)l, 16, 0, 0);
}

// ---- 1) fused prep: convert F/Txt/h -> bf16, 10 weights -> bf16 ----------
// 1D grid. Blocks [0,8192): F conv; [8192,9216): Txt; [9216,9232): h;
// [9232,9872): weight z=(bx-9232)>>6, 64x64 tile (bx-9232)&63.
// z: 0 Wav^T 1 Wat^T 2 Uav^T 3 Uat^T 4 Wb^T 5 Whh^T 6 Wve cvt 7 Wqe cvt
//    8 Vbv^T 9 Vbt^T
__global__ void k_prep(const float* __restrict__ F, const float* __restrict__ Txt,
                       const float* __restrict__ h,
                       const float* __restrict__ Wav, const float* __restrict__ Wat,
                       const float* __restrict__ Uav, const float* __restrict__ Uat,
                       const float* __restrict__ Wb,  const float* __restrict__ Whh,
                       const float* __restrict__ Wve, const float* __restrict__ Wqe,
                       const float* __restrict__ Vbv, const float* __restrict__ Vbt,
                       unsigned short* __restrict__ Fb, unsigned short* __restrict__ Tb,
                       unsigned short* __restrict__ hb, unsigned short* __restrict__ Wbf) {
  __shared__ float tile[64][65];
  const int bx = blockIdx.x, tid = threadIdx.x;
  if (bx < 9232) {   // conversion region: 2048 elems per block
    const float* src; unsigned short* dst; size_t base;
    if (bx < 8192)      { base = (size_t)bx * 2048;          src = F;   dst = Fb; }
    else if (bx < 9216) { base = (size_t)(bx - 8192) * 2048; src = Txt; dst = Tb; }
    else                { base = (size_t)(bx - 9216) * 2048; src = h;   dst = hb; }
    size_t i = base + (size_t)tid * 8;
    float4 f0 = *(const float4*)(src + i);
    float4 f1 = *(const float4*)(src + i + 4);
    uint4 p;
    p.x = pk2bf(f0.x, f0.y); p.y = pk2bf(f0.z, f0.w);
    p.z = pk2bf(f1.x, f1.y); p.w = pk2bf(f1.z, f1.w);
    *(uint4*)(dst + i) = p;
    return;
  }
  const int z = (bx - 9232) >> 6;
  const int t = (bx - 9232) & 63;
  const int k0 = (t >> 3) * 64, j0 = (t & 7) * 64;
  const float* src =
      (z == 0) ? Wav : (z == 1) ? Wat : (z == 2) ? Uav : (z == 3) ? Uat :
      (z == 4) ? Wb  : (z == 5) ? Whh : (z == 6) ? Wve : (z == 7) ? Wqe :
      (z == 8) ? Vbv : Vbt;
  unsigned short* dst = Wbf + (size_t)z * H * H;
  if (z == 6 || z == 7) {          // straight convert
    for (int i = 0; i < 16; ++i) {
      int e = tid + i * 256; int r = e >> 6, c = e & 63;
      dst[(size_t)(k0 + r) * H + j0 + c] = f2bf(src[(size_t)(k0 + r) * H + j0 + c]);
    }
    return;
  }
  for (int i = 0; i < 16; ++i) {
    int e = tid + i * 256; int r = e >> 6, c = e & 63;
    tile[r][c] = src[(size_t)(k0 + r) * H + j0 + c];
  }
  __syncthreads();
  for (int i = 0; i < 16; ++i) {
    int e = tid + i * 256; int r = e >> 6, c = e & 63;
    dst[(size_t)(j0 + r) * H + k0 + c] = f2bf(tile[c][r]);
  }
}

// ---- 2) phase-A GEMM: CA[seg][64][512] = hb @ Wbf[2+seg]^T ---------------
// seg 0 uv(+bav) 1 ut(+bat) 2 wbs 3 hwhh.  grid (8,4) block 256.
__global__ __launch_bounds__(256)
void k_gemmA(const unsigned short* __restrict__ A0, const unsigned short* __restrict__ Bt,
             float* __restrict__ C,
             const float* __restrict__ bias0, const float* __restrict__ bias1) {
  __shared__ unsigned short As[64 * 32];
  __shared__ unsigned short Bs[64 * 32];
  const int tid = threadIdx.x;
  const int n0 = blockIdx.x * 64;
  const int seg = blockIdx.y;
  const unsigned short* B = Bt + (size_t)seg * H * H;

  const int r = tid >> 2, c = (tid & 3) * 8;
  const unsigned short* Ag = A0 + (size_t)r * H + c;
  const unsigned short* Bg = B + (size_t)(n0 + r) * H + c;
  unsigned short* Al = &As[tid * 8];
  unsigned short* Bl = &Bs[tid * 8];

  const int wv = tid >> 6, ln = tid & 63;
  const int quad = ln >> 4, l16 = ln & 15;
  const int wm = (wv >> 1) * 32, wn = (wv & 1) * 32;

  f4v acc[2][2] = {};
  for (int k0 = 0; k0 < H; k0 += 32) {
    __syncthreads();
    gld16(Ag + k0, Al);
    gld16(Bg + k0, Bl);
    __syncthreads();
    s8v afr[2], bfr[2];
#pragma unroll
    for (int mi = 0; mi < 2; ++mi)
      afr[mi] = *(const s8v*)&As[(wm + mi * 16 + l16) * 32 + quad * 8];
#pragma unroll
    for (int ni = 0; ni < 2; ++ni)
      bfr[ni] = *(const s8v*)&Bs[(wn + ni * 16 + l16) * 32 + quad * 8];
#pragma unroll
    for (int mi = 0; mi < 2; ++mi)
#pragma unroll
      for (int ni = 0; ni < 2; ++ni)
        acc[mi][ni] = __builtin_amdgcn_mfma_f32_16x16x32_bf16(afr[mi], bfr[ni], acc[mi][ni], 0, 0, 0);
  }

  const float* bias = (seg == 0) ? bias0 : (seg == 1) ? bias1 : nullptr;
  float* Cs = C + (size_t)seg * BB * H;
#pragma unroll
  for (int mi = 0; mi < 2; ++mi)
#pragma unroll
    for (int ni = 0; ni < 2; ++ni)
#pragma unroll
      for (int rr = 0; rr < 4; ++rr) {
        const int row = wm + mi * 16 + quad * 4 + rr;
        const int j = n0 + wn + ni * 16 + l16;
        float v = acc[mi][ni][rr];
        if (bias) v += bias[j];
        Cs[(size_t)row * H + j] = v;
      }
}

// ---- 3) score GEMM — barrier-free wave-level tiles -----------------------
// One wave (64 threads) per block, 128x64 tile, BK=32, private LDS staging,
// NO __syncthreads: per-wave vmcnt waits overlap across ~8 resident waves/CU
// instead of block-wide barrier drains (the R4-R7 ceiling).
// grid (288, 8): bx<256 frames (m0=bx*128, LOGT=9), else text. n0=by*64.
// score pre-zeroed (atomicAdd partials over 8 n-tiles).
__global__ __launch_bounds__(64)
void k_score(const unsigned short* __restrict__ Fb, const unsigned short* __restrict__ Tb,
             const unsigned short* __restrict__ Wbf,
             const float* __restrict__ uv, const float* __restrict__ ut,
             const float* __restrict__ Vav, const float* __restrict__ Vat,
             float* __restrict__ score_v, float* __restrict__ score_t) {
  __shared__ unsigned short As[128 * 32];  // 8 KB
  __shared__ unsigned short Bs[64 * 32];   // 4 KB
  const int ln = threadIdx.x;              // 0..63
  const int bx = blockIdx.x;
  const bool fr = bx < 256;
  const int m0 = (fr ? bx : bx - 256) * 128;
  const int n0 = blockIdx.y * 64;
  const int logT = fr ? 9 : 6;
  const unsigned short* A = fr ? Fb : Tb;
  const unsigned short* Bt = fr ? Wbf : (Wbf + (size_t)H * H);
  const float* uvw = fr ? uv : ut;
  const float* V = fr ? Vav : Vat;
  float* score = fr ? score_v : score_t;

  const int quad = ln >> 4, l16 = ln & 15;

  // staging: granule g of row r at LDS short-offset r*32 + (g)*8; lanes cover
  // 16 rows x 4 granules per gld16 (monotone, coalesced 64B/row segments)
  const int ar = ln >> 2, ac = (ln & 3) * 8;
  const unsigned short* Ag = A + (size_t)(m0 + ar) * H + ac;
  const unsigned short* Bg = Bt + (size_t)(n0 + ar) * H + ac;
  unsigned short* Al = &As[ln * 8];
  unsigned short* Bl = &Bs[ln * 8];

  f4v acc[8][4] = {};

  for (int k0 = 0; k0 < H; k0 += 32) {
#pragma unroll
    for (int i = 0; i < 8; ++i)      // A: 128 rows
      gld16(Ag + (size_t)(i * 16) * H + k0, Al + i * 512);
#pragma unroll
    for (int i = 0; i < 4; ++i)      // B: 64 rows
      gld16(Bg + (size_t)(i * 16) * H + k0, Bl + i * 512);
    // compiler inserts the per-wave vmcnt/lgkm waits; no block barrier.
    s8v bfr[4];
#pragma unroll
    for (int ni = 0; ni < 4; ++ni)
      bfr[ni] = *(const s8v*)&Bs[(ni * 16 + l16) * 32 + quad * 8];
#pragma unroll
    for (int mi = 0; mi < 8; ++mi) {
      s8v afr = *(const s8v*)&As[(mi * 16 + l16) * 32 + quad * 8];
#pragma unroll
      for (int ni = 0; ni < 4; ++ni)
        acc[mi][ni] = __builtin_amdgcn_mfma_f32_16x16x32_bf16(afr, bfr[ni], acc[mi][ni], 0, 0, 0);
    }
  }

  int jj[4]; float vv[4];
#pragma unroll
  for (int ni = 0; ni < 4; ++ni) {
    jj[ni] = n0 + ni * 16 + l16;
    vv[ni] = V[jj[ni]];
  }
  const int tmask = (1 << logT) - 1;
#pragma unroll
  for (int mi = 0; mi < 8; ++mi) {
    const int mrow0 = m0 + mi * 16;
    const int bidx = mrow0 >> logT;
    const float* up = uvw + (size_t)bidx * H;
    float uu[4];
#pragma unroll
    for (int ni = 0; ni < 4; ++ni) uu[ni] = up[jj[ni]];
#pragma unroll
    for (int r = 0; r < 4; ++r) {
      float sum = 0.f;
#pragma unroll
      for (int ni = 0; ni < 4; ++ni)
        sum += fast_tanh(acc[mi][ni][r] + uu[ni]) * vv[ni];
      sum += __shfl_xor(sum, 1);
      sum += __shfl_xor(sum, 2);
      sum += __shfl_xor(sum, 4);
      sum += __shfl_xor(sum, 8);
      if (l16 == 0) {
        const int mrow = mrow0 + quad * 4 + r;
        atomicAdd(&score[((size_t)bidx << logT) + (mrow & tmask)], sum);
      }
    }
  }
}

// ---- 4) fused softmax + weighted sum ------------------------------------
// grid (64, 9): ch<8 frames t-chunk of 64; ch==8 text. hv/ht_sum pre-zeroed.
__global__ void k_wsum(const unsigned short* __restrict__ Fb, const unsigned short* __restrict__ Tb,
                       const float* __restrict__ score_v, const float* __restrict__ score_t,
                       float* __restrict__ hv_sum, float* __restrict__ ht_sum) {
  __shared__ float w[64];
  __shared__ float red[4];
  const int b = blockIdx.x, ch = blockIdx.y, tid = threadIdx.x;
  const bool fr = ch < 8;
  const float* sc = fr ? (score_v + b * TV) : (score_t + b * TT);
  const int T = fr ? TV : TT;

  float v0 = (tid < T) ? sc[tid] : -1e30f;
  float v1 = fr ? sc[tid + 256] : -1e30f;
  float mx = fmaxf(v0, v1);
  for (int d = 32; d; d >>= 1) mx = fmaxf(mx, __shfl_xor(mx, d));
  if ((tid & 63) == 0) red[tid >> 6] = mx;
  __syncthreads();
  mx = fmaxf(fmaxf(red[0], red[1]), fmaxf(red[2], red[3]));
  __syncthreads();
  float e0 = (tid < T) ? __expf(v0 - mx) : 0.f;
  float e1 = fr ? __expf(v1 - mx) : 0.f;
  float se = e0 + e1;
  for (int d = 32; d; d >>= 1) se += __shfl_xor(se, d);
  if ((tid & 63) == 0) red[tid >> 6] = se;
  __syncthreads();
  const float inv = 1.f / (red[0] + red[1] + red[2] + red[3]);
  const int t0 = fr ? ch * 64 : 0;
  if (tid < 64) w[tid] = __expf(sc[t0 + tid] - mx) * inv;
  __syncthreads();

  const unsigned short* X = fr ? (Fb + ((size_t)b * TV + t0) * H)
                               : (Tb + (size_t)b * TT * H);
  float* out = fr ? (hv_sum + b * H) : (ht_sum + b * H);
  const int j = tid * 2;
  float a0 = 0.f, a1 = 0.f;
  for (int t = 0; t < 64; ++t) {
    unsigned u = *(const unsigned*)(X + (size_t)t * H + j);
    float wt = w[t];
    a0 += wt * __uint_as_float(u << 16);
    a1 += wt * __uint_as_float(u & 0xffff0000u);
  }
  atomicAdd(&out[j], a0);
  atomicAdd(&out[j + 1], a1);
}

// ---- 5) phase-B GEMM + fused gate ---------------------------------------
// seg 0: hv@Wve^T -> CB0; 1: ht@Wqe^T -> CB1;
// seg 2: hv@Vbv -> gate reduce atomicAdd sArr[0..63];
// seg 3: ht@Vbt -> gate reduce atomicAdd sArr[64..127].  sArr pre-zeroed.
// grid (8,4), block 256. A staged fp32->bf16 in-kernel.
__global__ __launch_bounds__(256)
void k_gemmB(const float* __restrict__ Afp, const unsigned short* __restrict__ Bt,
             float* __restrict__ C, const float* __restrict__ wbs,
             const float* __restrict__ bbv, const float* __restrict__ bbt,
             const float* __restrict__ wb, float* __restrict__ sArr) {
  __shared__ unsigned short As[64 * 32];
  __shared__ unsigned short Bs[64 * 32];
  const int tid = threadIdx.x;
  const int n0 = blockIdx.x * 64;
  const int seg = blockIdx.y;
  const float* A = Afp + (size_t)((seg & 1) ? BB * H : 0);
  const unsigned short* B = Bt + (size_t)seg * H * H;

  const int r = tid >> 2, c = (tid & 3) * 8;
  const float* Ag = A + (size_t)r * H + c;
  const unsigned short* Bg = B + (size_t)(n0 + r) * H + c;
  unsigned short* Bl = &Bs[tid * 8];

  const int wv = tid >> 6, ln = tid & 63;
  const int quad = ln >> 4, l16 = ln & 15;
  const int wm = (wv >> 1) * 32, wn = (wv & 1) * 32;

  f4v acc[2][2] = {};
  for (int k0 = 0; k0 < H; k0 += 32) {
    __syncthreads();
    float4 f0 = *(const float4*)(Ag + k0);
    float4 f1 = *(const float4*)(Ag + k0 + 4);
    uint4 p;
    p.x = pk2bf(f0.x, f0.y); p.y = pk2bf(f0.z, f0.w);
    p.z = pk2bf(f1.x, f1.y); p.w = pk2bf(f1.z, f1.w);
    *(uint4*)&As[tid * 8] = p;
    gld16(Bg + k0, Bl);
    __syncthreads();
    s8v afr[2], bfr[2];
#pragma unroll
    for (int mi = 0; mi < 2; ++mi)
      afr[mi] = *(const s8v*)&As[(wm + mi * 16 + l16) * 32 + quad * 8];
#pragma unroll
    for (int ni = 0; ni < 2; ++ni)
      bfr[ni] = *(const s8v*)&Bs[(wn + ni * 16 + l16) * 32 + quad * 8];
#pragma unroll
    for (int mi = 0; mi < 2; ++mi)
#pragma unroll
      for (int ni = 0; ni < 2; ++ni)
        acc[mi][ni] = __builtin_amdgcn_mfma_f32_16x16x32_bf16(afr[mi], bfr[ni], acc[mi][ni], 0, 0, 0);
  }

  if (seg < 2) {
    float* Cs = C + (size_t)seg * BB * H;
#pragma unroll
    for (int mi = 0; mi < 2; ++mi)
#pragma unroll
      for (int ni = 0; ni < 2; ++ni)
#pragma unroll
        for (int rr = 0; rr < 4; ++rr) {
          const int row = wm + mi * 16 + quad * 4 + rr;
          const int j = n0 + wn + ni * 16 + l16;
          Cs[(size_t)row * H + j] = acc[mi][ni][rr];
        }
  } else {
    // gate: m1 = acc + wbs + b2; contrib = tanh(m1)*wb; reduce over block cols
    const float* b2 = (seg == 2) ? bbv : bbt;
    const int sbase = (seg == 2) ? 0 : BB;
#pragma unroll
    for (int mi = 0; mi < 2; ++mi)
#pragma unroll
      for (int rr = 0; rr < 4; ++rr) {
        const int row = wm + mi * 16 + quad * 4 + rr;   // batch b
        float sum = 0.f;
#pragma unroll
        for (int ni = 0; ni < 2; ++ni) {
          const int j = n0 + wn + ni * 16 + l16;
          float g = acc[mi][ni][rr] + wbs[(size_t)row * H + j] + b2[j];
          sum += fast_tanh(g) * wb[j];
        }
        sum += __shfl_xor(sum, 1);
        sum += __shfl_xor(sum, 2);
        sum += __shfl_xor(sum, 4);
        sum += __shfl_xor(sum, 8);
        if (l16 == 0) atomicAdd(&sArr[sbase + row], sum);
      }
  }
}

// ---- 6) beta softmax + output (folds bve/bqe) ----------------------------
__global__ void k_final2(const float* __restrict__ sArr, const float* __restrict__ hwhh,
                         const float* __restrict__ bh,
                         const float* __restrict__ hv2, const float* __restrict__ ht2,
                         const float* __restrict__ bve, const float* __restrict__ bqe,
                         float* __restrict__ out) {
  __shared__ float red[4];
  const int b = blockIdx.x, tid = threadIdx.x;
  float v = (tid < 2 * BB) ? sArr[tid] : -1e30f;
  float mx = v;
  for (int d = 32; d; d >>= 1) mx = fmaxf(mx, __shfl_xor(mx, d));
  if ((tid & 63) == 0) red[tid >> 6] = mx;
  __syncthreads();
  mx = fmaxf(fmaxf(red[0], red[1]), fmaxf(red[2], red[3]));
  __syncthreads();
  float e = (tid < 2 * BB) ? __expf(v - mx) : 0.f;
  for (int d = 32; d; d >>= 1) e += __shfl_xor(e, d);
  if ((tid & 63) == 0) red[tid >> 6] = e;
  __syncthreads();
  const float Z = red[0] + red[1] + red[2] + red[3];
  const float beta0 = __expf(sArr[0] - mx) / Z;
  const float beta1 = __expf(sArr[1] - mx) / Z;
#pragma unroll
  for (int jj = 0; jj < 2; ++jj) {
    int j = tid + jj * 256;
    float x = hwhh[(size_t)b * H + j] + bh[j]
            + beta0 * (hv2[(size_t)b * H + j] + bve[j])
            + beta1 * (ht2[(size_t)b * H + j] + bqe[j]);
    out[(size_t)b * H + j] = fast_tanh(x);
  }
}

// ---- launch --------------------------------------------------------------

extern "C" void kernel_launch(void* const* d_in, const int* in_sizes, int n_in,
                              void* d_out, int out_size, void* d_ws, size_t ws_size,
                              hipStream_t stream) {
  const float* h    = (const float*)d_in[0];
  const float* F    = (const float*)d_in[1];
  const float* Txt  = (const float*)d_in[2];
  const float* Wav  = (const float*)d_in[3];
  const float* Wat  = (const float*)d_in[4];
  const float* Uav  = (const float*)d_in[5];
  const float* Uat  = (const float*)d_in[6];
  const float* Vav  = (const float*)d_in[7];
  const float* Vat  = (const float*)d_in[8];
  const float* bav  = (const float*)d_in[9];
  const float* bat  = (const float*)d_in[10];
  const float* Whh  = (const float*)d_in[11];
  const float* bh   = (const float*)d_in[12];
  const float* Wve  = (const float*)d_in[13];
  const float* bve  = (const float*)d_in[14];
  const float* Wqe  = (const float*)d_in[15];
  const float* bqe  = (const float*)d_in[16];
  const float* Wb   = (const float*)d_in[17];
  const float* Vbv  = (const float*)d_in[18];
  const float* Vbt  = (const float*)d_in[19];
  const float* bbv  = (const float*)d_in[20];
  const float* bbt  = (const float*)d_in[21];
  const float* wb   = (const float*)d_in[22];
  float* out = (float*)d_out;

  char* ws = (char*)d_ws;
  size_t off = 0;
  auto alloc = [&](size_t bytes) -> void* {
    void* p = ws + off;
    off += (bytes + 255) & ~(size_t)255;
    return p;
  };
  // zero-init region contiguous: score_v, score_t, hv_sum, ht_sum, sArr
  float* score_v = (float*)alloc((size_t)BB * TV * 4);   // 131072 B
  float* score_t = (float*)alloc((size_t)BB * TT * 4);   //  16384 B
  float* hv_sum  = (float*)alloc((size_t)BB * H * 4);    // 131072 B
  float* ht_sum  = (float*)alloc((size_t)BB * H * 4);    // 131072 B
  float* sArr    = (float*)alloc((size_t)2 * BB * 4);    //    512 B
  unsigned short* Wbf = (unsigned short*)alloc((size_t)10 * H * H * 2);  // 5.24 MB
  unsigned short* Fb  = (unsigned short*)alloc((size_t)BB * TV * H * 2); // 33.5 MB
  unsigned short* Tb  = (unsigned short*)alloc((size_t)BB * TT * H * 2); // 4.2 MB
  unsigned short* hb  = (unsigned short*)alloc((size_t)BB * H * 2);
  float* CA   = (float*)alloc((size_t)4 * BB * H * 4);   // uv|ut|wbs|hwhh
  float* CB   = (float*)alloc((size_t)2 * BB * H * 4);   // hv2'|ht2'

  float* uv   = CA;
  float* ut   = CA + (size_t)BB * H;
  float* wbs  = CA + (size_t)2 * BB * H;
  float* hwhh = CA + (size_t)3 * BB * H;

  hipMemsetAsync(score_v, 0,
                 (size_t)(BB * TV + BB * TT + 2 * BB * H + 2 * BB) * 4, stream);

  k_prep<<<dim3(9872), 256, 0, stream>>>(F, Txt, h, Wav, Wat, Uav, Uat, Wb, Whh,
                                         Wve, Wqe, Vbv, Vbt, Fb, Tb, hb, Wbf);
  k_gemmA<<<dim3(8, 4), 256, 0, stream>>>(hb, Wbf + (size_t)2 * H * H, CA, bav, bat);
  k_score<<<dim3(288, 8), 64, 0, stream>>>(Fb, Tb, Wbf, uv, ut, Vav, Vat,
                                           score_v, score_t);
  k_wsum<<<dim3(64, 9), 256, 0, stream>>>(Fb, Tb, score_v, score_t, hv_sum, ht_sum);
  k_gemmB<<<dim3(8, 4), 256, 0, stream>>>(hv_sum, Wbf + (size_t)6 * H * H, CB,
                                          wbs, bbv, bbt, wb, sArr);
  k_final2<<<64, 256, 0, stream>>>(sArr, hwhh, bh, CB, CB + (size_t)BB * H,
                                   bve, bqe, out);
}

// Round 9
// 219.317 us; speedup vs baseline: 1.2684x; 1.2684x over previous
//
#include <hip/hip_runtime.h>
#include <stdint.h>
#include <stddef.h>

#define H  512
#define BB 64
#define TV 512
#define TT 64

typedef short s8v __attribute__((ext_vector_type(8)));   // 8 bf16 (4 VGPRs)
typedef float f4v __attribute__((ext_vector_type(4)));   // MFMA accumulator

// ---- helpers -------------------------------------------------------------

__device__ inline unsigned short f2bf(float f) {
  unsigned int u = __float_as_uint(f);
  u = (u + 0x7fffu + ((u >> 16) & 1u)) >> 16;   // RNE
  return (unsigned short)u;
}

__device__ inline unsigned int pk2bf(float lo, float hi) {
  unsigned int a = __float_as_uint(lo);
  a = (a + 0x7fffu + ((a >> 16) & 1u)) >> 16;
  unsigned int b = __float_as_uint(hi);
  b = (b + 0x7fffu + ((b >> 16) & 1u)) & 0xffff0000u;
  return a | b;
}

__device__ inline float fast_tanh(float x) {
  x = fminf(15.f, fmaxf(-15.f, x));
  float e = __expf(2.f * x);
  return (e - 1.f) * __builtin_amdgcn_rcpf(e + 1.f);
}

// async global->LDS, 16 bytes per lane (global_load_lds_dwordx4).
// R6 lesson: per-lane global addresses must stay monotone/contiguous.
// R8 lesson: barrier-free single-wave blocks kill residency (128 AGPR acc
// -> 1 wave/SIMD); the overlap resource is multiple small BLOCKS per CU.
__device__ inline void gld16(const unsigned short* g, unsigned short* l) {
  __builtin_amdgcn_global_load_lds(
      (const __attribute__((address_space(1))) unsigned int*)g,
      (__attribute__((address_space(3))) unsigned int*)l, 16, 0, 0);
}

// ---- 1) fused prep: convert F/Txt/h -> bf16, 10 weights -> bf16 ----------
// 1D grid. Blocks [0,8192): F conv; [8192,9216): Txt; [9216,9232): h;
// [9232,9872): weight z=(bx-9232)>>6, 64x64 tile (bx-9232)&63.
// z: 0 Wav^T 1 Wat^T 2 Uav^T 3 Uat^T 4 Wb^T 5 Whh^T 6 Wve cvt 7 Wqe cvt
//    8 Vbv^T 9 Vbt^T
__global__ void k_prep(const float* __restrict__ F, const float* __restrict__ Txt,
                       const float* __restrict__ h,
                       const float* __restrict__ Wav, const float* __restrict__ Wat,
                       const float* __restrict__ Uav, const float* __restrict__ Uat,
                       const float* __restrict__ Wb,  const float* __restrict__ Whh,
                       const float* __restrict__ Wve, const float* __restrict__ Wqe,
                       const float* __restrict__ Vbv, const float* __restrict__ Vbt,
                       unsigned short* __restrict__ Fb, unsigned short* __restrict__ Tb,
                       unsigned short* __restrict__ hb, unsigned short* __restrict__ Wbf) {
  __shared__ float tile[64][65];
  const int bx = blockIdx.x, tid = threadIdx.x;
  if (bx < 9232) {   // conversion region: 2048 elems per block
    const float* src; unsigned short* dst; size_t base;
    if (bx < 8192)      { base = (size_t)bx * 2048;          src = F;   dst = Fb; }
    else if (bx < 9216) { base = (size_t)(bx - 8192) * 2048; src = Txt; dst = Tb; }
    else                { base = (size_t)(bx - 9216) * 2048; src = h;   dst = hb; }
    size_t i = base + (size_t)tid * 8;
    float4 f0 = *(const float4*)(src + i);
    float4 f1 = *(const float4*)(src + i + 4);
    uint4 p;
    p.x = pk2bf(f0.x, f0.y); p.y = pk2bf(f0.z, f0.w);
    p.z = pk2bf(f1.x, f1.y); p.w = pk2bf(f1.z, f1.w);
    *(uint4*)(dst + i) = p;
    return;
  }
  const int z = (bx - 9232) >> 6;
  const int t = (bx - 9232) & 63;
  const int k0 = (t >> 3) * 64, j0 = (t & 7) * 64;
  const float* src =
      (z == 0) ? Wav : (z == 1) ? Wat : (z == 2) ? Uav : (z == 3) ? Uat :
      (z == 4) ? Wb  : (z == 5) ? Whh : (z == 6) ? Wve : (z == 7) ? Wqe :
      (z == 8) ? Vbv : Vbt;
  unsigned short* dst = Wbf + (size_t)z * H * H;
  if (z == 6 || z == 7) {          // straight convert
    for (int i = 0; i < 16; ++i) {
      int e = tid + i * 256; int r = e >> 6, c = e & 63;
      dst[(size_t)(k0 + r) * H + j0 + c] = f2bf(src[(size_t)(k0 + r) * H + j0 + c]);
    }
    return;
  }
  for (int i = 0; i < 16; ++i) {
    int e = tid + i * 256; int r = e >> 6, c = e & 63;
    tile[r][c] = src[(size_t)(k0 + r) * H + j0 + c];
  }
  __syncthreads();
  for (int i = 0; i < 16; ++i) {
    int e = tid + i * 256; int r = e >> 6, c = e & 63;
    dst[(size_t)(j0 + r) * H + k0 + c] = f2bf(tile[c][r]);
  }
}

// ---- 2) phase-A GEMM: CA[seg][64][512] = hb @ Wbf[2+seg]^T ---------------
// seg 0 uv(+bav) 1 ut(+bat) 2 wbs 3 hwhh.  grid (8,4) block 256.
__global__ __launch_bounds__(256)
void k_gemmA(const unsigned short* __restrict__ A0, const unsigned short* __restrict__ Bt,
             float* __restrict__ C,
             const float* __restrict__ bias0, const float* __restrict__ bias1) {
  __shared__ unsigned short As[64 * 32];
  __shared__ unsigned short Bs[64 * 32];
  const int tid = threadIdx.x;
  const int n0 = blockIdx.x * 64;
  const int seg = blockIdx.y;
  const unsigned short* B = Bt + (size_t)seg * H * H;

  const int r = tid >> 2, c = (tid & 3) * 8;
  const unsigned short* Ag = A0 + (size_t)r * H + c;
  const unsigned short* Bg = B + (size_t)(n0 + r) * H + c;
  unsigned short* Al = &As[tid * 8];
  unsigned short* Bl = &Bs[tid * 8];

  const int wv = tid >> 6, ln = tid & 63;
  const int quad = ln >> 4, l16 = ln & 15;
  const int wm = (wv >> 1) * 32, wn = (wv & 1) * 32;

  f4v acc[2][2] = {};
  for (int k0 = 0; k0 < H; k0 += 32) {
    __syncthreads();
    gld16(Ag + k0, Al);
    gld16(Bg + k0, Bl);
    __syncthreads();
    s8v afr[2], bfr[2];
#pragma unroll
    for (int mi = 0; mi < 2; ++mi)
      afr[mi] = *(const s8v*)&As[(wm + mi * 16 + l16) * 32 + quad * 8];
#pragma unroll
    for (int ni = 0; ni < 2; ++ni)
      bfr[ni] = *(const s8v*)&Bs[(wn + ni * 16 + l16) * 32 + quad * 8];
#pragma unroll
    for (int mi = 0; mi < 2; ++mi)
#pragma unroll
      for (int ni = 0; ni < 2; ++ni)
        acc[mi][ni] = __builtin_amdgcn_mfma_f32_16x16x32_bf16(afr[mi], bfr[ni], acc[mi][ni], 0, 0, 0);
  }

  const float* bias = (seg == 0) ? bias0 : (seg == 1) ? bias1 : nullptr;
  float* Cs = C + (size_t)seg * BB * H;
#pragma unroll
  for (int mi = 0; mi < 2; ++mi)
#pragma unroll
    for (int ni = 0; ni < 2; ++ni)
#pragma unroll
      for (int rr = 0; rr < 4; ++rr) {
        const int row = wm + mi * 16 + quad * 4 + rr;
        const int j = n0 + wn + ni * 16 + l16;
        float v = acc[mi][ni][rr];
        if (bias) v += bias[j];
        Cs[(size_t)row * H + j] = v;
      }
}

// ---- 3) score GEMM — 64x128 tiles, more blocks/CU for drain overlap ------
// 2-barrier structure (proven), but smaller tiles: grid (576, 4) = 2304
// blocks -> ~6 resident/CU (LDS 12 KB, VGPR ~80). A block's barrier drain
// only stalls its own waves; ~6 independent blocks interleave per CU.
// bx<512: frames m0=bx*64, LOGT=9; else text m0=(bx-512)*64, LOGT=6.
// score pre-zeroed (atomicAdd partials over 4 n-tiles).
__global__ __launch_bounds__(256)
void k_score(const unsigned short* __restrict__ Fb, const unsigned short* __restrict__ Tb,
             const unsigned short* __restrict__ Wbf,
             const float* __restrict__ uv, const float* __restrict__ ut,
             const float* __restrict__ Vav, const float* __restrict__ Vat,
             float* __restrict__ score_v, float* __restrict__ score_t) {
  __shared__ unsigned short As[64 * 32];    // 4 KB
  __shared__ unsigned short Bs[128 * 32];   // 8 KB
  const int tid = threadIdx.x;
  const int bx = blockIdx.x;
  const bool fr = bx < 512;
  const int m0 = (fr ? bx : bx - 512) * 64;
  const int n0 = blockIdx.y * 128;
  const int logT = fr ? 9 : 6;
  const unsigned short* A = fr ? Fb : Tb;
  const unsigned short* Bt = fr ? Wbf : (Wbf + (size_t)H * H);
  const float* uvw = fr ? uv : ut;
  const float* V = fr ? Vav : Vat;
  float* score = fr ? score_v : score_t;

  const int wv = tid >> 6, ln = tid & 63;
  const int quad = ln >> 4, l16 = ln & 15;
  const int wm = (wv >> 1) * 32, wn = (wv & 1) * 64;

  // staging. B: 256 slots, slot sb = wv*64+ln (all 4 waves).
  //          A: 128 slots, slot sa = wv*64+ln for waves 0,1 only.
  const int sb = wv * 64 + ln;
  const int rb = sb >> 2, cb = (sb & 3) * 8;
  const unsigned short* Bg = Bt + (size_t)(n0 + rb) * H + cb;
  unsigned short* Bl = &Bs[sb * 8];
  const int sa = sb;                       // valid when wv<2
  const int ra = sa >> 2, ca = (sa & 3) * 8;
  const unsigned short* Ag = A + (size_t)(m0 + ra) * H + ca;
  unsigned short* Al = &As[sa * 8];
  const bool doA = (wv < 2);

  f4v acc[2][4] = {};

  for (int k0 = 0; k0 < H; k0 += 32) {
    __syncthreads();
    if (doA) gld16(Ag + k0, Al);
    gld16(Bg + k0, Bl);
    __syncthreads();
    s8v afr[2], bfr[4];
#pragma unroll
    for (int mi = 0; mi < 2; ++mi)
      afr[mi] = *(const s8v*)&As[(wm + mi * 16 + l16) * 32 + quad * 8];
#pragma unroll
    for (int ni = 0; ni < 4; ++ni)
      bfr[ni] = *(const s8v*)&Bs[(wn + ni * 16 + l16) * 32 + quad * 8];
#pragma unroll
    for (int mi = 0; mi < 2; ++mi)
#pragma unroll
      for (int ni = 0; ni < 4; ++ni)
        acc[mi][ni] = __builtin_amdgcn_mfma_f32_16x16x32_bf16(afr[mi], bfr[ni], acc[mi][ni], 0, 0, 0);
  }

  int jj[4]; float vv[4];
#pragma unroll
  for (int ni = 0; ni < 4; ++ni) {
    jj[ni] = n0 + wn + ni * 16 + l16;
    vv[ni] = V[jj[ni]];
  }
  const int tmask = (1 << logT) - 1;
#pragma unroll
  for (int mi = 0; mi < 2; ++mi) {
    const int mrow0 = m0 + wm + mi * 16;
    const int bidx = mrow0 >> logT;
    const float* up = uvw + (size_t)bidx * H;
    float uu[4];
#pragma unroll
    for (int ni = 0; ni < 4; ++ni) uu[ni] = up[jj[ni]];
#pragma unroll
    for (int r = 0; r < 4; ++r) {
      float sum = 0.f;
#pragma unroll
      for (int ni = 0; ni < 4; ++ni)
        sum += fast_tanh(acc[mi][ni][r] + uu[ni]) * vv[ni];
      sum += __shfl_xor(sum, 1);
      sum += __shfl_xor(sum, 2);
      sum += __shfl_xor(sum, 4);
      sum += __shfl_xor(sum, 8);
      if (l16 == 0) {
        const int mrow = mrow0 + quad * 4 + r;
        atomicAdd(&score[((size_t)bidx << logT) + (mrow & tmask)], sum);
      }
    }
  }
}

// ---- 4) fused softmax + weighted sum ------------------------------------
// grid (64, 9): ch<8 frames t-chunk of 64; ch==8 text. hv/ht_sum pre-zeroed.
__global__ void k_wsum(const unsigned short* __restrict__ Fb, const unsigned short* __restrict__ Tb,
                       const float* __restrict__ score_v, const float* __restrict__ score_t,
                       float* __restrict__ hv_sum, float* __restrict__ ht_sum) {
  __shared__ float w[64];
  __shared__ float red[4];
  const int b = blockIdx.x, ch = blockIdx.y, tid = threadIdx.x;
  const bool fr = ch < 8;
  const float* sc = fr ? (score_v + b * TV) : (score_t + b * TT);
  const int T = fr ? TV : TT;

  float v0 = (tid < T) ? sc[tid] : -1e30f;
  float v1 = fr ? sc[tid + 256] : -1e30f;
  float mx = fmaxf(v0, v1);
  for (int d = 32; d; d >>= 1) mx = fmaxf(mx, __shfl_xor(mx, d));
  if ((tid & 63) == 0) red[tid >> 6] = mx;
  __syncthreads();
  mx = fmaxf(fmaxf(red[0], red[1]), fmaxf(red[2], red[3]));
  __syncthreads();
  float e0 = (tid < T) ? __expf(v0 - mx) : 0.f;
  float e1 = fr ? __expf(v1 - mx) : 0.f;
  float se = e0 + e1;
  for (int d = 32; d; d >>= 1) se += __shfl_xor(se, d);
  if ((tid & 63) == 0) red[tid >> 6] = se;
  __syncthreads();
  const float inv = 1.f / (red[0] + red[1] + red[2] + red[3]);
  const int t0 = fr ? ch * 64 : 0;
  if (tid < 64) w[tid] = __expf(sc[t0 + tid] - mx) * inv;
  __syncthreads();

  const unsigned short* X = fr ? (Fb + ((size_t)b * TV + t0) * H)
                               : (Tb + (size_t)b * TT * H);
  float* out = fr ? (hv_sum + b * H) : (ht_sum + b * H);
  const int j = tid * 2;
  float a0 = 0.f, a1 = 0.f;
  for (int t = 0; t < 64; ++t) {
    unsigned u = *(const unsigned*)(X + (size_t)t * H + j);
    float wt = w[t];
    a0 += wt * __uint_as_float(u << 16);
    a1 += wt * __uint_as_float(u & 0xffff0000u);
  }
  atomicAdd(&out[j], a0);
  atomicAdd(&out[j + 1], a1);
}

// ---- 5) phase-B GEMM + fused gate ---------------------------------------
// seg 0: hv@Wve^T -> CB0; 1: ht@Wqe^T -> CB1;
// seg 2: hv@Vbv -> gate reduce atomicAdd sArr[0..63];
// seg 3: ht@Vbt -> gate reduce atomicAdd sArr[64..127].  sArr pre-zeroed.
// grid (8,4), block 256. A staged fp32->bf16 in-kernel.
__global__ __launch_bounds__(256)
void k_gemmB(const float* __restrict__ Afp, const unsigned short* __restrict__ Bt,
             float* __restrict__ C, const float* __restrict__ wbs,
             const float* __restrict__ bbv, const float* __restrict__ bbt,
             const float* __restrict__ wb, float* __restrict__ sArr) {
  __shared__ unsigned short As[64 * 32];
  __shared__ unsigned short Bs[64 * 32];
  const int tid = threadIdx.x;
  const int n0 = blockIdx.x * 64;
  const int seg = blockIdx.y;
  const float* A = Afp + (size_t)((seg & 1) ? BB * H : 0);
  const unsigned short* B = Bt + (size_t)seg * H * H;

  const int r = tid >> 2, c = (tid & 3) * 8;
  const float* Ag = A + (size_t)r * H + c;
  const unsigned short* Bg = B + (size_t)(n0 + r) * H + c;
  unsigned short* Bl = &Bs[tid * 8];

  const int wv = tid >> 6, ln = tid & 63;
  const int quad = ln >> 4, l16 = ln & 15;
  const int wm = (wv >> 1) * 32, wn = (wv & 1) * 32;

  f4v acc[2][2] = {};
  for (int k0 = 0; k0 < H; k0 += 32) {
    __syncthreads();
    float4 f0 = *(const float4*)(Ag + k0);
    float4 f1 = *(const float4*)(Ag + k0 + 4);
    uint4 p;
    p.x = pk2bf(f0.x, f0.y); p.y = pk2bf(f0.z, f0.w);
    p.z = pk2bf(f1.x, f1.y); p.w = pk2bf(f1.z, f1.w);
    *(uint4*)&As[tid * 8] = p;
    gld16(Bg + k0, Bl);
    __syncthreads();
    s8v afr[2], bfr[2];
#pragma unroll
    for (int mi = 0; mi < 2; ++mi)
      afr[mi] = *(const s8v*)&As[(wm + mi * 16 + l16) * 32 + quad * 8];
#pragma unroll
    for (int ni = 0; ni < 2; ++ni)
      bfr[ni] = *(const s8v*)&Bs[(wn + ni * 16 + l16) * 32 + quad * 8];
#pragma unroll
    for (int mi = 0; mi < 2; ++mi)
#pragma unroll
      for (int ni = 0; ni < 2; ++ni)
        acc[mi][ni] = __builtin_amdgcn_mfma_f32_16x16x32_bf16(afr[mi], bfr[ni], acc[mi][ni], 0, 0, 0);
  }

  if (seg < 2) {
    float* Cs = C + (size_t)seg * BB * H;
#pragma unroll
    for (int mi = 0; mi < 2; ++mi)
#pragma unroll
      for (int ni = 0; ni < 2; ++ni)
#pragma unroll
        for (int rr = 0; rr < 4; ++rr) {
          const int row = wm + mi * 16 + quad * 4 + rr;
          const int j = n0 + wn + ni * 16 + l16;
          Cs[(size_t)row * H + j] = acc[mi][ni][rr];
        }
  } else {
    // gate: m1 = acc + wbs + b2; contrib = tanh(m1)*wb; reduce over block cols
    const float* b2 = (seg == 2) ? bbv : bbt;
    const int sbase = (seg == 2) ? 0 : BB;
#pragma unroll
    for (int mi = 0; mi < 2; ++mi)
#pragma unroll
      for (int rr = 0; rr < 4; ++rr) {
        const int row = wm + mi * 16 + quad * 4 + rr;   // batch b
        float sum = 0.f;
#pragma unroll
        for (int ni = 0; ni < 2; ++ni) {
          const int j = n0 + wn + ni * 16 + l16;
          float g = acc[mi][ni][rr] + wbs[(size_t)row * H + j] + b2[j];
          sum += fast_tanh(g) * wb[j];
        }
        sum += __shfl_xor(sum, 1);
        sum += __shfl_xor(sum, 2);
        sum += __shfl_xor(sum, 4);
        sum += __shfl_xor(sum, 8);
        if (l16 == 0) atomicAdd(&sArr[sbase + row], sum);
      }
  }
}

// ---- 6) beta softmax + output (folds bve/bqe) ----------------------------
__global__ void k_final2(const float* __restrict__ sArr, const float* __restrict__ hwhh,
                         const float* __restrict__ bh,
                         const float* __restrict__ hv2, const float* __restrict__ ht2,
                         const float* __restrict__ bve, const float* __restrict__ bqe,
                         float* __restrict__ out) {
  __shared__ float red[4];
  const int b = blockIdx.x, tid = threadIdx.x;
  float v = (tid < 2 * BB) ? sArr[tid] : -1e30f;
  float mx = v;
  for (int d = 32; d; d >>= 1) mx = fmaxf(mx, __shfl_xor(mx, d));
  if ((tid & 63) == 0) red[tid >> 6] = mx;
  __syncthreads();
  mx = fmaxf(fmaxf(red[0], red[1]), fmaxf(red[2], red[3]));
  __syncthreads();
  float e = (tid < 2 * BB) ? __expf(v - mx) : 0.f;
  for (int d = 32; d; d >>= 1) e += __shfl_xor(e, d);
  if ((tid & 63) == 0) red[tid >> 6] = e;
  __syncthreads();
  const float Z = red[0] + red[1] + red[2] + red[3];
  const float beta0 = __expf(sArr[0] - mx) / Z;
  const float beta1 = __expf(sArr[1] - mx) / Z;
#pragma unroll
  for (int jj = 0; jj < 2; ++jj) {
    int j = tid + jj * 256;
    float x = hwhh[(size_t)b * H + j] + bh[j]
            + beta0 * (hv2[(size_t)b * H + j] + bve[j])
            + beta1 * (ht2[(size_t)b * H + j] + bqe[j]);
    out[(size_t)b * H + j] = fast_tanh(x);
  }
}

// ---- launch --------------------------------------------------------------

extern "C" void kernel_launch(void* const* d_in, const int* in_sizes, int n_in,
                              void* d_out, int out_size, void* d_ws, size_t ws_size,
                              hipStream_t stream) {
  const float* h    = (const float*)d_in[0];
  const float* F    = (const float*)d_in[1];
  const float* Txt  = (const float*)d_in[2];
  const float* Wav  = (const float*)d_in[3];
  const float* Wat  = (const float*)d_in[4];
  const float* Uav  = (const float*)d_in[5];
  const float* Uat  = (const float*)d_in[6];
  const float* Vav  = (const float*)d_in[7];
  const float* Vat  = (const float*)d_in[8];
  const float* bav  = (const float*)d_in[9];
  const float* bat  = (const float*)d_in[10];
  const float* Whh  = (const float*)d_in[11];
  const float* bh   = (const float*)d_in[12];
  const float* Wve  = (const float*)d_in[13];
  const float* bve  = (const float*)d_in[14];
  const float* Wqe  = (const float*)d_in[15];
  const float* bqe  = (const float*)d_in[16];
  const float* Wb   = (const float*)d_in[17];
  const float* Vbv  = (const float*)d_in[18];
  const float* Vbt  = (const float*)d_in[19];
  const float* bbv  = (const float*)d_in[20];
  const float* bbt  = (const float*)d_in[21];
  const float* wb   = (const float*)d_in[22];
  float* out = (float*)d_out;

  char* ws = (char*)d_ws;
  size_t off = 0;
  auto alloc = [&](size_t bytes) -> void* {
    void* p = ws + off;
    off += (bytes + 255) & ~(size_t)255;
    return p;
  };
  // zero-init region contiguous: score_v, score_t, hv_sum, ht_sum, sArr
  float* score_v = (float*)alloc((size_t)BB * TV * 4);   // 131072 B
  float* score_t = (float*)alloc((size_t)BB * TT * 4);   //  16384 B
  float* hv_sum  = (float*)alloc((size_t)BB * H * 4);    // 131072 B
  float* ht_sum  = (float*)alloc((size_t)BB * H * 4);    // 131072 B
  float* sArr    = (float*)alloc((size_t)2 * BB * 4);    //    512 B
  unsigned short* Wbf = (unsigned short*)alloc((size_t)10 * H * H * 2);  // 5.24 MB
  unsigned short* Fb  = (unsigned short*)alloc((size_t)BB * TV * H * 2); // 33.5 MB
  unsigned short* Tb  = (unsigned short*)alloc((size_t)BB * TT * H * 2); // 4.2 MB
  unsigned short* hb  = (unsigned short*)alloc((size_t)BB * H * 2);
  float* CA   = (float*)alloc((size_t)4 * BB * H * 4);   // uv|ut|wbs|hwhh
  float* CB   = (float*)alloc((size_t)2 * BB * H * 4);   // hv2'|ht2'

  float* uv   = CA;
  float* ut   = CA + (size_t)BB * H;
  float* wbs  = CA + (size_t)2 * BB * H;
  float* hwhh = CA + (size_t)3 * BB * H;

  hipMemsetAsync(score_v, 0,
                 (size_t)(BB * TV + BB * TT + 2 * BB * H + 2 * BB) * 4, stream);

  k_prep<<<dim3(9872), 256, 0, stream>>>(F, Txt, h, Wav, Wat, Uav, Uat, Wb, Whh,
                                         Wve, Wqe, Vbv, Vbt, Fb, Tb, hb, Wbf);
  k_gemmA<<<dim3(8, 4), 256, 0, stream>>>(hb, Wbf + (size_t)2 * H * H, CA, bav, bat);
  k_score<<<dim3(576, 4), 256, 0, stream>>>(Fb, Tb, Wbf, uv, ut, Vav, Vat,
                                            score_v, score_t);
  k_wsum<<<dim3(64, 9), 256, 0, stream>>>(Fb, Tb, score_v, score_t, hv_sum, ht_sum);
  k_gemmB<<<dim3(8, 4), 256, 0, stream>>>(hv_sum, Wbf + (size_t)6 * H * H, CB,
                                          wbs, bbv, bbt, wb, sArr);
  k_final2<<<64, 256, 0, stream>>>(sArr, hwhh, bh, CB, CB + (size_t)BB * H,
                                   bve, bqe, out);
}